// Round 7
// baseline (238.604 us; speedup 1.0000x reference)
//
#include <hip/hip_runtime.h>
#include <hip/hip_bf16.h>

// Problem constants: N=50000, K=32, D=128.
#define D     128
#define TWO_D 256
#define KNB   32

typedef __attribute__((ext_vector_type(8))) short    s8;   // 8 x 16-bit (4 VGPR)
typedef __attribute__((ext_vector_type(8))) _Float16 h8;   // mfma operand view
typedef __attribute__((ext_vector_type(2))) _Float16 h2v;
typedef __attribute__((ext_vector_type(4))) float    f4;   // MFMA acc

__device__ inline unsigned short f2h(float f) {
    return __builtin_bit_cast(unsigned short, (_Float16)f);
}
__device__ inline float h2f(unsigned int u) {
    return (float)__builtin_bit_cast(_Float16, (unsigned short)u);
}

union v16u { s8 s; h2v h[4]; };

// 8-elem fp16 dot with f32 accumulate; v_dot2_f32_f16 when available.
__device__ inline float dot8(s8 x, s8 w, float acc) {
#if __has_builtin(__builtin_amdgcn_fdot2)
    v16u ux, uw; ux.s = x; uw.s = w;
#pragma unroll
    for (int j = 0; j < 4; ++j)
        acc = __builtin_amdgcn_fdot2(ux.h[j], uw.h[j], acc, false);
#else
#pragma unroll
    for (int j = 0; j < 8; ++j)
        acc = fmaf(h2f((unsigned short)x[j]), h2f((unsigned short)w[j]), acc);
#endif
    return acc;
}

// Async global->LDS, 16 B per lane. LDS dest = wave-uniform base + lane*16.
__device__ __forceinline__ void gload16(const void* g, void* l) {
    __builtin_amdgcn_global_load_lds(
        (__attribute__((address_space(1))) void*)g,
        (__attribute__((address_space(3))) void*)l, 16, 0, 0);
}

// ---------------------------------------------------------------------------
// Cast kernel: v_fea, t_emb (f32) -> vh, th (fp16 bits). ~15 us. (r5-proven)
// ---------------------------------------------------------------------------
__global__ __launch_bounds__(256) void cast_kernel(
    const float* __restrict__ a, const float* __restrict__ b,
    unsigned short* __restrict__ oa, unsigned short* __restrict__ ob, int n4)
{
    int i = blockIdx.x * 256 + threadIdx.x;
    if (i >= n4) return;
    float4 x = ((const float4*)a)[i];
    float4 y = ((const float4*)b)[i];
    ushort4 px = make_ushort4(f2h(x.x), f2h(x.y), f2h(x.z), f2h(x.w));
    ushort4 py = make_ushort4(f2h(y.x), f2h(y.y), f2h(y.z), f2h(y.w));
    ((ushort4*)oa)[i] = px;
    ((ushort4*)ob)[i] = py;
}

// ---------------------------------------------------------------------------
// Kernel A: wq = [vh | th] @ W^T via fp16 MFMA. BM=128 rows, BN=64 cols,
// BK=64. Grid (391, 4) = 1564 blocks (~6/CU). A read fp16 direct; W f32
// inline-cvt (both r5-proven paths). wq stored fp16.
// ---------------------------------------------------------------------------
#define BM 128
#define BN 64
#define BK 64
#define LDT 72   // row stride (elems): 144 B, 16B-aligned; rows 8 apart alias = 2-way (free)

__global__ __launch_bounds__(256) void gemm_wq_mfma(
    const unsigned short* __restrict__ vh, const unsigned short* __restrict__ th,
    const float* __restrict__ W, unsigned short* __restrict__ wq_h, int M)
{
    __shared__ unsigned short As[BM][LDT];   // 18.4 KB
    __shared__ unsigned short Bs[BN][LDT];   //  9.2 KB

    const int tid  = threadIdx.x;
    const int w    = tid >> 6;
    const int lane = tid & 63;
    const int quad = lane >> 4;
    const int l16  = lane & 15;
    const int row0 = blockIdx.x * BM;
    const int i0   = blockIdx.y * BN;

    f4 acc[2][4] = {};

    // A staging: 128 rows x 64 cols fp16; 2 thr/row, 32 cols (4 s8) each.
    const int arow = tid >> 1;
    const int acol = (tid & 1) * 32;
    int ga = row0 + arow; if (ga >= M) ga = M - 1;   // clamp (stores guarded)
    // B staging: 64 rows x 64 cols from W f32; 4 thr/row, 16 cols (4 float4).
    const int brow = tid >> 2;
    const int bcol = (tid & 3) * 16;

    for (int kt = 0; kt < TWO_D; kt += BK) {
        const unsigned short* srcA = (kt < D) ? vh : th;
        const int kb = kt & (D - 1);
        const unsigned short* pa = srcA + (size_t)ga * D + kb + acol;
        s8 a0 = *(const s8*)(pa);
        s8 a1 = *(const s8*)(pa + 8);
        s8 a2 = *(const s8*)(pa + 16);
        s8 a3 = *(const s8*)(pa + 24);
        const float* pb = W + (size_t)(i0 + brow) * TWO_D + kt + bcol;
        float4 b0 = *(const float4*)(pb);
        float4 b1 = *(const float4*)(pb + 4);
        float4 b2 = *(const float4*)(pb + 8);
        float4 b3 = *(const float4*)(pb + 12);

        __syncthreads();   // prior iter's frag reads done before overwrite
        *(s8*)&As[arow][acol]      = a0;
        *(s8*)&As[arow][acol + 8]  = a1;
        *(s8*)&As[arow][acol + 16] = a2;
        *(s8*)&As[arow][acol + 24] = a3;
        {
            s8 q0, q1;
            q0[0]=(short)f2h(b0.x); q0[1]=(short)f2h(b0.y); q0[2]=(short)f2h(b0.z); q0[3]=(short)f2h(b0.w);
            q0[4]=(short)f2h(b1.x); q0[5]=(short)f2h(b1.y); q0[6]=(short)f2h(b1.z); q0[7]=(short)f2h(b1.w);
            q1[0]=(short)f2h(b2.x); q1[1]=(short)f2h(b2.y); q1[2]=(short)f2h(b2.z); q1[3]=(short)f2h(b2.w);
            q1[4]=(short)f2h(b3.x); q1[5]=(short)f2h(b3.y); q1[6]=(short)f2h(b3.z); q1[7]=(short)f2h(b3.w);
            *(s8*)&Bs[brow][bcol]     = q0;
            *(s8*)&Bs[brow][bcol + 8] = q1;
        }
        __syncthreads();

        // Wave w: rows [w*32, w*32+32) (2 m-tiles), 4 n-tiles, 2 k-steps.
#pragma unroll
        for (int s = 0; s < 2; ++s) {
            s8 af0 = *(const s8*)&As[w * 32 + l16][s * 32 + quad * 8];
            s8 af1 = *(const s8*)&As[w * 32 + 16 + l16][s * 32 + quad * 8];
#pragma unroll
            for (int nt = 0; nt < 4; ++nt) {
                s8 bf = *(const s8*)&Bs[nt * 16 + l16][s * 32 + quad * 8];
                acc[0][nt] = __builtin_amdgcn_mfma_f32_16x16x32_f16(
                    __builtin_bit_cast(h8, af0), __builtin_bit_cast(h8, bf), acc[0][nt], 0, 0, 0);
                acc[1][nt] = __builtin_amdgcn_mfma_f32_16x16x32_f16(
                    __builtin_bit_cast(h8, af1), __builtin_bit_cast(h8, bf), acc[1][nt], 0, 0, 0);
            }
        }
    }

    // Epilogue: D layout col=lane&15, row=quad*4+r.
#pragma unroll
    for (int mt = 0; mt < 2; ++mt) {
#pragma unroll
        for (int nt = 0; nt < 4; ++nt) {
#pragma unroll
            for (int r = 0; r < 4; ++r) {
                int grow = row0 + w * 32 + mt * 16 + quad * 4 + r;
                if (grow < M)
                    wq_h[(size_t)grow * TWO_D + i0 + nt * 16 + l16] = f2h(acc[mt][nt][r]);
            }
        }
    }
}

// ---------------------------------------------------------------------------
// Kernel B: gather + score + softmax + weighted sum. One wave per row,
// 2 waves (128 thr) per block. Phase A: 17 async global_load_lds per wave
// (32 edges x {v,t} + wq row) -> wave-private 17 KB LDS slice; one
// __syncthreads drains vmcnt. Phase B: pure LDS.
//   chunk kk (1 KB): [v(e_2kk) 256B | v(e_2kk+1) | t(e_2kk) | t(e_2kk+1)]
//   wq slice at 16384: halves 0..255 contiguous (512 B used of 1 KB).
// Scores: lane l<32 -> v-half of edge l; lane l>=32 -> t-half of edge l-32.
// Each lane does the full 128-elem half-dot (16 bank-rotated b128 reads),
// fold via shfl_xor(32). No parking dance.
// ---------------------------------------------------------------------------
__global__ __launch_bounds__(128) void attn_kernel(
    const unsigned short* __restrict__ vh, const unsigned short* __restrict__ th,
    const int* __restrict__ ef, const unsigned short* __restrict__ wq_h,
    float* __restrict__ outp, int M)
{
    __shared__ char L[2][17408];   // 34 KB: per wave 16 KB chunks + 1 KB wq

    const int lane = threadIdx.x & 63;
    const int w    = threadIdx.x >> 6;
    const int n    = blockIdx.x * 2 + w;   // grid*2 == M exactly (50000)
    if (n >= M) return;

    char* Lw = &L[w][0];
    const int l16  = lane & 15;
    const int gsel = (lane >> 4) & 1;      // 0: even edge, 1: odd edge
    const unsigned short* gsrc = (lane < 32) ? vh : th;

    int eidx = 0;
    if (lane < KNB) eidx = ef[n * KNB + lane];

    // ---- Phase A: async direct-to-LDS copies (no VGPR results => compiler
    // cannot sink them; all 17 stay in flight until the barrier drain) ----
    gload16(wq_h + (size_t)n * TWO_D + lane * 8, Lw + 16384);
#pragma unroll
    for (int kk = 0; kk < 16; ++kk) {
        int e = __shfl(eidx, 2 * kk + gsel, 64);
        gload16(gsrc + (size_t)e * D + l16 * 8, Lw + kk * 1024);
    }
    __syncthreads();   // emits s_waitcnt vmcnt(0) before s_barrier: data landed

    // ---- Scores: one lane per (edge, half) ----
    const int k     = lane & 31;
    const int tsel  = lane >> 5;                       // 0: v-half, 1: t-half
    const int dbase = (k >> 1) * 1024 + (k & 1) * 256 + tsel * 512;
    const int cbase = 16384 + tsel * 256;
    float p = 0.f;
#pragma unroll
    for (int j = 0; j < 16; ++j) {
        int jl = ((j + lane) & 15) * 16;   // bank rotation; data & coeff use same slice
        s8 x = *(const s8*)(Lw + dbase + jl);
        s8 c = *(const s8*)(Lw + cbase + jl);
        p = dot8(x, c, p);
    }
    p += __shfl_xor(p, 32, 64);            // lane k (<32) now holds score_k

    // softmax over lanes 0..31 (lanes 32..63 compute unused garbage)
    float mx = p;
#pragma unroll
    for (int off = 16; off > 0; off >>= 1) mx = fmaxf(mx, __shfl_xor(mx, off, 64));
    float ex  = __expf(p - mx);
    float sum = ex;
#pragma unroll
    for (int off = 16; off > 0; off >>= 1) sum += __shfl_xor(sum, off, 64);
    float r = ex / sum;

    // ---- Weighted sum: lane covers d = (lane&31)*4 .. +3; lanes<32 do even
    // edges, lanes>=32 odd edges; fold via shfl_xor(32). ----
    float o4[4] = {0.f, 0.f, 0.f, 0.f};
    const int g   = lane >> 5;
    const int dby = (lane & 31) * 8;
#pragma unroll
    for (int kk = 0; kk < 16; ++kk) {
        float rk = __shfl(r, 2 * kk + g, 64);
        uint2 pq = *(const uint2*)(Lw + kk * 1024 + g * 256 + dby);
        o4[0] = fmaf(rk, h2f(pq.x & 0xFFFFu), o4[0]);
        o4[1] = fmaf(rk, h2f(pq.x >> 16),     o4[1]);
        o4[2] = fmaf(rk, h2f(pq.y & 0xFFFFu), o4[2]);
        o4[3] = fmaf(rk, h2f(pq.y >> 16),     o4[3]);
    }
#pragma unroll
    for (int j = 0; j < 4; ++j) o4[j] += __shfl_xor(o4[j], 32, 64);

    if (lane < 32)
        *(float4*)(outp + (size_t)n * D + (lane & 31) * 4) =
            make_float4(o4[0], o4[1], o4[2], o4[3]);
}

// ---------------------------------------------------------------------------
extern "C" void kernel_launch(void* const* d_in, const int* in_sizes, int n_in,
                              void* d_out, int out_size, void* d_ws, size_t ws_size,
                              hipStream_t stream)
{
    const float* v_fea = (const float*)d_in[0];
    const float* t_emb = (const float*)d_in[1];
    const int*   ef    = (const int*)d_in[2];
    const float* W     = (const float*)d_in[3];
    float* outp = (float*)d_out;

    const int M = in_sizes[0] / D;                  // 50000
    // ws layout: wq_h (fp16, 25.6 MB) | vh (12.8 MB) | th (12.8 MB) = 51.2 MB
    char* ws = (char*)d_ws;
    unsigned short* wq_h = (unsigned short*)ws;
    unsigned short* vh   = (unsigned short*)(ws + (size_t)M * TWO_D * 2);
    unsigned short* th   = (unsigned short*)(ws + (size_t)M * TWO_D * 2 + (size_t)M * D * 2);

    const int n4 = M * D / 4;
    cast_kernel<<<(n4 + 255) / 256, 256, 0, stream>>>(v_fea, t_emb, vh, th, n4);

    dim3 gg((M + BM - 1) / BM, TWO_D / BN);
    gemm_wq_mfma<<<gg, 256, 0, stream>>>(vh, th, W, wq_h, M);
    attn_kernel<<<M / 2, 128, 0, stream>>>(vh, th, ef, wq_h, outp, M);
}